// Round 5
// baseline (399.870 us; speedup 1.0000x reference)
//
#include <hip/hip_runtime.h>
#include <hip/hip_bf16.h>
#include <math.h>

#define BE   256
#define DIM  256
#define OUTD 128
#define LCL  256
#define LEV  512
#define NEGV -1e18f

typedef short  bf16x8  __attribute__((ext_vector_type(8)));
typedef float  floatx4 __attribute__((ext_vector_type(4)));

union BF1 { __hip_bfloat16 h; unsigned short u; };
union BF2 { __hip_bfloat162 h; unsigned int u; };

__device__ __forceinline__ float fast_tanh(float x) {
    float xc = fminf(fmaxf(x, -15.f), 15.f);
    float e = __expf(2.f * xc);                       // e^{2x}
    return (e - 1.f) * __builtin_amdgcn_rcpf(e + 1.f);
}

// Direct global->LDS DMA, 16B per lane. Dest is wave-uniform base
// (HW writes lane i at base + i*16); source is per-lane.
__device__ __forceinline__ void gl_lds16(const float4* g, float4* l) {
    __builtin_amdgcn_global_load_lds(
        (const __attribute__((address_space(1))) unsigned int*)(const void*)g,
        (__attribute__((address_space(3))) unsigned int*)(void*)l,
        16, 0, 0);
}

// ---------------------------------------------------------------------------
// K1: per-pair means (float4 streaming, unroll 8) + bias GEMVs + WT fold.
// blocks [0,256): pair b. blocks 256,257: W[:D] -> bf16 W^T.
// ---------------------------------------------------------------------------
__global__ __launch_bounds__(512) void k_meanbias(
    const float* __restrict__ claim, const float* __restrict__ evidence,
    const float* __restrict__ W1, const float* __restrict__ W2,
    float* __restrict__ bias_e, float* __restrict__ bias_c,
    unsigned short* __restrict__ WT1, unsigned short* __restrict__ WT2)
{
    const int bid = blockIdx.x;
    const int t = threadIdx.x;
    if (bid >= BE) {
        const int side = bid - BE;
        const float* W = side ? W2 : W1;
        unsigned short* WT = side ? WT2 : WT1;
        for (int i = t; i < OUTD * DIM; i += 512) {
            const int d = i & (DIM - 1);
            const int n = i >> 8;
            BF1 c; c.h = __float2bfloat16(W[(size_t)d * OUTD + n]);
            WT[n * DIM + d] = c.u;
        }
        return;
    }
    const int pair = bid;
    const int d4 = t & 63, rg = t >> 6;      // 8 row groups
    __shared__ float4 smc[8][64];
    __shared__ float4 sme[8][64];
    __shared__ float mc[DIM], me[DIM];
    __shared__ float sb[2][2][OUTD];

    const float4* c4 = (const float4*)(claim + (size_t)pair * LCL * DIM);
    const float4* e4 = (const float4*)(evidence + (size_t)pair * LEV * DIM);
    float4 ac = make_float4(0.f, 0.f, 0.f, 0.f);
    float4 ae = make_float4(0.f, 0.f, 0.f, 0.f);
#pragma unroll 8
    for (int r = rg; r < LCL; r += 8) {
        const float4 v = c4[r * 64 + d4];
        ac.x += v.x; ac.y += v.y; ac.z += v.z; ac.w += v.w;
    }
#pragma unroll 8
    for (int r = rg; r < LEV; r += 8) {
        const float4 v = e4[r * 64 + d4];
        ae.x += v.x; ae.y += v.y; ae.z += v.z; ae.w += v.w;
    }
    smc[rg][d4] = ac; sme[rg][d4] = ae;
    __syncthreads();
    if (t < 64) {
        float4 s = make_float4(0.f, 0.f, 0.f, 0.f);
#pragma unroll
        for (int j = 0; j < 8; ++j) {
            const float4 v = smc[j][t];
            s.x += v.x; s.y += v.y; s.z += v.z; s.w += v.w;
        }
        ((float4*)mc)[t] = make_float4(s.x * (1.f / LCL), s.y * (1.f / LCL),
                                       s.z * (1.f / LCL), s.w * (1.f / LCL));
    } else if (t < 128) {
        const int u = t - 64;
        float4 s = make_float4(0.f, 0.f, 0.f, 0.f);
#pragma unroll
        for (int j = 0; j < 8; ++j) {
            const float4 v = sme[j][u];
            s.x += v.x; s.y += v.y; s.z += v.z; s.w += v.w;
        }
        ((float4*)me)[u] = make_float4(s.x * (1.f / LEV), s.y * (1.f / LEV),
                                       s.z * (1.f / LEV), s.w * (1.f / LEV));
    }
    __syncthreads();
    const int side = t >> 8, o = t & 127, dh = (t >> 7) & 1;
    const float* W = side ? W2 : W1;
    const float* m = side ? me : mc;
    float s = 0.f;
#pragma unroll 8
    for (int i = 0; i < 128; ++i) {
        const int d = dh * 128 + i;
        s += m[d] * W[(size_t)(DIM + d) * OUTD + o];
    }
    sb[side][dh][o] = s;
    __syncthreads();
    if (t < 256) {
        const int sd = t >> 7, oo = t & 127;
        const float bv = sb[sd][0][oo] + sb[sd][1][oo];
        (sd ? bias_c : bias_e)[pair * OUTD + oo] = bv;
    }
}

// ---------------------------------------------------------------------------
// K2: fused scores + online-softmax + weighted sum. One block per (pair,side),
// parity-interleaved: even bid = evidence (L=512), odd = claim (L=256).
// 32-row double-buffered fp32 tiles (67 KB -> 2 blocks/CU, 16 waves).
// Raw barriers: vmcnt(0) drained ONLY at tile top; mid-tile barrier waits
// lgkmcnt only, so the next-tile DMA stays in flight across the whole tile
// (R4's __syncthreads drained vmcnt(0) mid-tile -> DMA serialized vs compute).
// Online softmax computed redundantly by ALL waves (registers m,l per wave,
// identical across waves) -> 2 barriers/tile, no wave0-serial section.
// ---------------------------------------------------------------------------
__global__ __launch_bounds__(512, 2) void k_fused(
    const float* __restrict__ claim, const float* __restrict__ evidence,
    const unsigned short* __restrict__ WT1, const unsigned short* __restrict__ WT2,
    const float* __restrict__ w2v, const float* __restrict__ w1v,
    const float* __restrict__ bias_e, const float* __restrict__ bias_c,
    const int* __restrict__ emask, const int* __restrict__ cmask,
    float* __restrict__ out)
{
    constexpr int TR  = 32;                 // tile rows
    constexpr int SR4 = 65;                 // row stride in float4
    __shared__ float4 sA4[2][TR * SR4];     // 2 x 33280 B
    __shared__ float sred[TR][4];

    const int bid = blockIdx.x;
    const bool is_ev = (bid & 1) == 0;
    const int pair = bid >> 1;
    const float* __restrict__ seq  = is_ev ? evidence : claim;
    const unsigned short* __restrict__ WT = is_ev ? WT1 : WT2;
    const float* __restrict__ wvec = is_ev ? w2v : w1v;
    const float* __restrict__ bias = is_ev ? bias_e : bias_c;
    const int*   __restrict__ mask = is_ev ? emask : cmask;
    float* __restrict__ outp       = is_ev ? out + (size_t)BE * DIM : out;
    const int L  = is_ev ? LEV : LCL;
    const int NT = L >> 5;                  // 32-row tiles: 16 (ev) / 8 (claim)

    const int t = threadIdx.x;
    const int lane = t & 63;
    const int wv = t >> 6;                  // 0..7
    const int wrowf = wv >> 2;              // 0..1 -> 16-row slice
    const int wcg = wv & 3;                 // 0..3 -> 32-col group
    const int q = lane >> 4, c16 = lane & 15;

    float bc[2], wc[2];
#pragma unroll
    for (int ct = 0; ct < 2; ++ct) {
        const int col = wcg * 32 + ct * 16 + c16;
        bc[ct] = bias[pair * OUTD + col];
        wc[ct] = wvec[col];
    }
    const unsigned short* wbase = WT + (size_t)(wcg * 32 + c16) * DIM + q * 8;
    const float4* sp4 = (const float4*)(seq + (size_t)pair * L * DIM);

    // each wave DMAs 4 rows (1KB each: 64 lanes x 16B, linear dest)
    auto stage = [&](int buf, int tile) {
        const float4* base = sp4 + (size_t)tile * (TR * 64);
#pragma unroll
        for (int j = 0; j < 4; ++j) {
            const int row = wv * 4 + j;
            gl_lds16(base + row * 64 + lane, &sA4[buf][row * SR4]);
        }
    };

    stage(0, 0);                            // prologue: tile 0 -> buf 0
    int cur = 0;

    float4 Oac = make_float4(0.f, 0.f, 0.f, 0.f);
    float m_run = -INFINITY, l_run = 0.f;

    for (int tile = 0; tile < NT; ++tile) {
        // buf[cur] DMA landed; all prev-tile LDS reads consumed pre-barrier
        asm volatile("s_waitcnt vmcnt(0) lgkmcnt(0)" ::: "memory");
        __builtin_amdgcn_s_barrier();
        if (tile + 1 < NT) stage(cur ^ 1, tile + 1);   // flies across whole tile

        // ---- MFMA scores: wave -> rows wrowf*16..+16, cols wcg*32..+32 ----
        floatx4 acc[2];
        acc[0] = (floatx4){0.f, 0.f, 0.f, 0.f};
        acc[1] = (floatx4){0.f, 0.f, 0.f, 0.f};
        const int arow = wrowf * 16 + c16;
#pragma unroll
        for (int ks = 0; ks < 8; ++ks) {
            bf16x8 bfr[2];
#pragma unroll
            for (int ct = 0; ct < 2; ++ct)
                bfr[ct] = *(const bf16x8*)(wbase + (size_t)ct * 16 * DIM + ks * 32);
            const float4 lo = sA4[cur][arow * SR4 + ks * 8 + q * 2];
            const float4 hi = sA4[cur][arow * SR4 + ks * 8 + q * 2 + 1];
            union { bf16x8 v; BF2 p[4]; } ua;
            ua.p[0].h = __float22bfloat162_rn(make_float2(lo.x, lo.y));
            ua.p[1].h = __float22bfloat162_rn(make_float2(lo.z, lo.w));
            ua.p[2].h = __float22bfloat162_rn(make_float2(hi.x, hi.y));
            ua.p[3].h = __float22bfloat162_rn(make_float2(hi.z, hi.w));
#pragma unroll
            for (int ct = 0; ct < 2; ++ct)
                acc[ct] = __builtin_amdgcn_mfma_f32_16x16x32_bf16(ua.v, bfr[ct], acc[ct], 0, 0, 0);
        }

        // ---- tanh-dot epilogue -> sred[row][colgroup] ----
#pragma unroll
        for (int reg = 0; reg < 4; ++reg) {
            float s = 0.f;
#pragma unroll
            for (int ct = 0; ct < 2; ++ct)
                s += fast_tanh(acc[ct][reg] + bc[ct]) * wc[ct];
#pragma unroll
            for (int off = 1; off < 16; off <<= 1) s += __shfl_xor(s, off, 64);
            if (c16 == 0)
                sred[wrowf * 16 + q * 4 + reg][wcg] = s;
        }
        // sred visible to all waves; DMA keeps flying (no vmcnt drain here)
        asm volatile("s_waitcnt lgkmcnt(0)" ::: "memory");
        __builtin_amdgcn_s_barrier();

        // ---- online softmax, redundantly in every wave (rows duplicated
        //      in lane halves; butterfly sum counts each row twice -> 0.5x) ----
        const int row = lane & 31;
        float a = sred[row][0] + sred[row][1] + sred[row][2] + sred[row][3];
        a = mask[pair * L + tile * TR + row] ? a : NEGV;
        float mx = a;
#pragma unroll
        for (int off = 1; off < 64; off <<= 1) mx = fmaxf(mx, __shfl_xor(mx, off, 64));
        const float newm = fmaxf(m_run, mx);
        const float e = __expf(a - newm);
        float sm = e;
#pragma unroll
        for (int off = 1; off < 64; off <<= 1) sm += __shfl_xor(sm, off, 64);
        const float scale = __expf(m_run - newm);   // first tile: 0
        l_run = l_run * scale + 0.5f * sm;
        m_run = newm;
        Oac.x *= scale; Oac.y *= scale; Oac.z *= scale; Oac.w *= scale;

        // ---- weighted sum from LDS fp32: wave wv covers rows wv*4..+4 ----
#pragma unroll
        for (int r = 0; r < 4; ++r) {
            const int rw = wv * 4 + r;
            const float pl = __shfl(e, rw, 64);
            const float4 v = sA4[cur][rw * SR4 + lane];
            Oac.x += pl * v.x; Oac.y += pl * v.y; Oac.z += pl * v.z; Oac.w += pl * v.w;
        }
        cur ^= 1;
    }

    // ---- cross-wave reduce (reuse sA4), normalize, store ----
    __syncthreads();
    ((float4*)sA4)[t] = Oac;
    __syncthreads();
    if (t < 64) {
        float4 s = make_float4(0.f, 0.f, 0.f, 0.f);
#pragma unroll
        for (int j = 0; j < 8; ++j) {
            const float4 v = ((float4*)sA4)[j * 64 + t];
            s.x += v.x; s.y += v.y; s.z += v.z; s.w += v.w;
        }
        const float inv = 1.f / l_run;
        ((float4*)(outp + (size_t)pair * DIM))[t] =
            make_float4(s.x * inv, s.y * inv, s.z * inv, s.w * inv);
    }
}

// ---------------------------------------------------------------------------
extern "C" void kernel_launch(void* const* d_in, const int* in_sizes, int n_in,
                              void* d_out, int out_size, void* d_ws, size_t ws_size,
                              hipStream_t stream) {
    const float* claim    = (const float*)d_in[0];
    const int*   cmask    = (const int*)  d_in[1];
    const float* evidence = (const float*)d_in[2];
    const int*   emask    = (const int*)  d_in[3];
    const float* W1       = (const float*)d_in[4];
    const float* w2       = (const float*)d_in[5];
    const float* W2       = (const float*)d_in[6];
    const float* w1       = (const float*)d_in[7];
    float* out = (float*)d_out;

    float* ws = (float*)d_ws;
    float* bias_e = ws;                          // 256*128
    float* bias_c = bias_e + BE * OUTD;          // 256*128
    unsigned short* WT1 = (unsigned short*)(bias_c + BE * OUTD);
    unsigned short* WT2 = WT1 + OUTD * DIM;

    k_meanbias<<<BE + 2, 512, 0, stream>>>(claim, evidence, W1, W2,
                                           bias_e, bias_c, WT1, WT2);
    // output order: c_hat first (claim side), e_hat second (evidence side)
    k_fused<<<2 * BE, 512, 0, stream>>>(claim, evidence, WT1, WT2, w2, w1,
                                        bias_e, bias_c, emask, cmask, out);
}

// Round 6
// 370.264 us; speedup vs baseline: 1.0800x; 1.0800x over previous
//
#include <hip/hip_runtime.h>
#include <hip/hip_bf16.h>
#include <math.h>

#define BE   256
#define DIM  256
#define OUTD 128
#define LCL  256
#define LEV  512
#define NEGV -1e18f

typedef short  bf16x8  __attribute__((ext_vector_type(8)));
typedef float  floatx4 __attribute__((ext_vector_type(4)));

union BF1 { __hip_bfloat16 h; unsigned short u; };
union BF2 { __hip_bfloat162 h; unsigned int u; };

__device__ __forceinline__ float fast_tanh(float x) {
    float xc = fminf(fmaxf(x, -15.f), 15.f);
    float e = __expf(2.f * xc);                       // e^{2x}
    return (e - 1.f) * __builtin_amdgcn_rcpf(e + 1.f);
}

// Direct global->LDS DMA, 16B per lane. Dest is wave-uniform base
// (HW writes lane i at base + i*16); source is per-lane.
__device__ __forceinline__ void gl_lds16(const float4* g, float4* l) {
    __builtin_amdgcn_global_load_lds(
        (const __attribute__((address_space(1))) unsigned int*)(const void*)g,
        (__attribute__((address_space(3))) unsigned int*)(void*)l,
        16, 0, 0);
}

// ---------------------------------------------------------------------------
// K1: per-pair means (float4 streaming, unroll 8) + bias GEMVs + WT fold.
// blocks [0,256): pair b. blocks 256,257: W[:D] -> bf16 W^T.
// ---------------------------------------------------------------------------
__global__ __launch_bounds__(512) void k_meanbias(
    const float* __restrict__ claim, const float* __restrict__ evidence,
    const float* __restrict__ W1, const float* __restrict__ W2,
    float* __restrict__ bias_e, float* __restrict__ bias_c,
    unsigned short* __restrict__ WT1, unsigned short* __restrict__ WT2)
{
    const int bid = blockIdx.x;
    const int t = threadIdx.x;
    if (bid >= BE) {
        const int side = bid - BE;
        const float* W = side ? W2 : W1;
        unsigned short* WT = side ? WT2 : WT1;
        for (int i = t; i < OUTD * DIM; i += 512) {
            const int d = i & (DIM - 1);
            const int n = i >> 8;
            BF1 c; c.h = __float2bfloat16(W[(size_t)d * OUTD + n]);
            WT[n * DIM + d] = c.u;
        }
        return;
    }
    const int pair = bid;
    const int d4 = t & 63, rg = t >> 6;      // 8 row groups
    __shared__ float4 smc[8][64];
    __shared__ float4 sme[8][64];
    __shared__ float mc[DIM], me[DIM];
    __shared__ float sb[2][2][OUTD];

    const float4* c4 = (const float4*)(claim + (size_t)pair * LCL * DIM);
    const float4* e4 = (const float4*)(evidence + (size_t)pair * LEV * DIM);
    float4 ac = make_float4(0.f, 0.f, 0.f, 0.f);
    float4 ae = make_float4(0.f, 0.f, 0.f, 0.f);
#pragma unroll 8
    for (int r = rg; r < LCL; r += 8) {
        const float4 v = c4[r * 64 + d4];
        ac.x += v.x; ac.y += v.y; ac.z += v.z; ac.w += v.w;
    }
#pragma unroll 8
    for (int r = rg; r < LEV; r += 8) {
        const float4 v = e4[r * 64 + d4];
        ae.x += v.x; ae.y += v.y; ae.z += v.z; ae.w += v.w;
    }
    smc[rg][d4] = ac; sme[rg][d4] = ae;
    __syncthreads();
    if (t < 64) {
        float4 s = make_float4(0.f, 0.f, 0.f, 0.f);
#pragma unroll
        for (int j = 0; j < 8; ++j) {
            const float4 v = smc[j][t];
            s.x += v.x; s.y += v.y; s.z += v.z; s.w += v.w;
        }
        ((float4*)mc)[t] = make_float4(s.x * (1.f / LCL), s.y * (1.f / LCL),
                                       s.z * (1.f / LCL), s.w * (1.f / LCL));
    } else if (t < 128) {
        const int u = t - 64;
        float4 s = make_float4(0.f, 0.f, 0.f, 0.f);
#pragma unroll
        for (int j = 0; j < 8; ++j) {
            const float4 v = sme[j][u];
            s.x += v.x; s.y += v.y; s.z += v.z; s.w += v.w;
        }
        ((float4*)me)[u] = make_float4(s.x * (1.f / LEV), s.y * (1.f / LEV),
                                       s.z * (1.f / LEV), s.w * (1.f / LEV));
    }
    __syncthreads();
    const int side = t >> 8, o = t & 127, dh = (t >> 7) & 1;
    const float* W = side ? W2 : W1;
    const float* m = side ? me : mc;
    float s = 0.f;
#pragma unroll 8
    for (int i = 0; i < 128; ++i) {
        const int d = dh * 128 + i;
        s += m[d] * W[(size_t)(DIM + d) * OUTD + o];
    }
    sb[side][dh][o] = s;
    __syncthreads();
    if (t < 256) {
        const int sd = t >> 7, oo = t & 127;
        const float bv = sb[sd][0][oo] + sb[sd][1][oo];
        (sd ? bias_c : bias_e)[pair * OUTD + oo] = bv;
    }
}

// ---------------------------------------------------------------------------
// K2: fused scores + online-softmax + weighted sum. One block per (pair,side),
// parity-interleaved: even bid = evidence (L=512), odd = claim (L=256).
// 64-row double-buffered fp32 tiles (133 KB LDS -> 1 block/CU), DMA-staged.
// B (WT) is preloaded into 16 bf16x8 REGISTERS before the loop -- R5's
// per-ks dependent global B-loads were the dominant per-tile serial cost
// (VGPR=52 showed the compiler never hoisted them). Counted waits: vmcnt(0)
// only at tile top (DMA flies across the whole tile body); mid barrier waits
// lgkmcnt only. Wave grid 2 (row) x 4 (col); softmax 1 row/lane, all waves.
// ---------------------------------------------------------------------------
__global__ __launch_bounds__(512, 1) void k_fused(
    const float* __restrict__ claim, const float* __restrict__ evidence,
    const unsigned short* __restrict__ WT1, const unsigned short* __restrict__ WT2,
    const float* __restrict__ w2v, const float* __restrict__ w1v,
    const float* __restrict__ bias_e, const float* __restrict__ bias_c,
    const int* __restrict__ emask, const int* __restrict__ cmask,
    float* __restrict__ out)
{
    constexpr int TR  = 64;                 // tile rows
    constexpr int SR4 = 65;                 // row stride in float4 (pad between rows)
    __shared__ float4 sA4[2][TR * SR4];     // 2 x 66560 B
    __shared__ float sred[4][TR];           // [colgroup][row]

    const int bid = blockIdx.x;
    const bool is_ev = (bid & 1) == 0;
    const int pair = bid >> 1;
    const float* __restrict__ seq  = is_ev ? evidence : claim;
    const unsigned short* __restrict__ WT = is_ev ? WT1 : WT2;
    const float* __restrict__ wvec = is_ev ? w2v : w1v;
    const float* __restrict__ bias = is_ev ? bias_e : bias_c;
    const int*   __restrict__ mask = is_ev ? emask : cmask;
    float* __restrict__ outp       = is_ev ? out + (size_t)BE * DIM : out;
    const int L  = is_ev ? LEV : LCL;
    const int NT = L >> 6;                  // 64-row tiles: 8 (ev) / 4 (claim)

    const int t = threadIdx.x;
    const int lane = t & 63;
    const int wv = t >> 6;                  // 0..7
    const int wrowf = wv >> 2;              // 0..1 -> 32-row slice
    const int wcg = wv & 3;                 // 0..3 -> 32-col group
    const int q = lane >> 4, c16 = lane & 15;
    const int arowb = wrowf * 32;

    float bc[2], wc[2];
#pragma unroll
    for (int ct = 0; ct < 2; ++ct) {
        const int col = wcg * 32 + ct * 16 + c16;
        bc[ct] = bias[pair * OUTD + col];
        wc[ct] = wvec[col];
    }

    // ---- preload all B fragments into registers (once per block) ----
    bf16x8 breg[16];
#pragma unroll
    for (int ks = 0; ks < 8; ++ks)
#pragma unroll
        for (int ct = 0; ct < 2; ++ct)
            breg[ks * 2 + ct] = *(const bf16x8*)(
                WT + (size_t)(wcg * 32 + ct * 16 + c16) * DIM + ks * 32 + q * 8);

    const float4* sp4 = (const float4*)(seq + (size_t)pair * L * DIM);

    // each wave DMAs 8 rows (1KB each: 64 lanes x 16B, linear dest)
    auto stage = [&](int buf, int tile) {
        const float4* base = sp4 + (size_t)tile * (TR * 64);
#pragma unroll
        for (int j = 0; j < 8; ++j) {
            const int row = wv * 8 + j;
            gl_lds16(base + row * 64 + lane, &sA4[buf][row * SR4]);
        }
    };

    stage(0, 0);                            // prologue: tile 0 -> buf 0
    int cur = 0;

    float4 Oac = make_float4(0.f, 0.f, 0.f, 0.f);
    float m_run = -INFINITY, l_run = 0.f;

    for (int tile = 0; tile < NT; ++tile) {
        // buf[cur] DMA landed; prev tile's LDS reads all pre-barrier
        asm volatile("s_waitcnt vmcnt(0) lgkmcnt(0)" ::: "memory");
        __builtin_amdgcn_s_barrier();
        if (tile + 1 < NT) stage(cur ^ 1, tile + 1);   // flies across whole tile
        const int mk = mask[pair * L + tile * TR + lane];  // prefetch mask word

        // ---- MFMA scores: wave -> rows arowb..+32, cols wcg*32..+32 ----
        floatx4 acc[2][2];
        acc[0][0] = (floatx4){0.f, 0.f, 0.f, 0.f};
        acc[0][1] = (floatx4){0.f, 0.f, 0.f, 0.f};
        acc[1][0] = (floatx4){0.f, 0.f, 0.f, 0.f};
        acc[1][1] = (floatx4){0.f, 0.f, 0.f, 0.f};
#pragma unroll
        for (int ks = 0; ks < 8; ++ks) {
#pragma unroll
            for (int ra = 0; ra < 2; ++ra) {
                const float4 lo = sA4[cur][(arowb + ra * 16 + c16) * SR4 + ks * 8 + q * 2];
                const float4 hi = sA4[cur][(arowb + ra * 16 + c16) * SR4 + ks * 8 + q * 2 + 1];
                union { bf16x8 v; BF2 p[4]; } ua;
                ua.p[0].h = __float22bfloat162_rn(make_float2(lo.x, lo.y));
                ua.p[1].h = __float22bfloat162_rn(make_float2(lo.z, lo.w));
                ua.p[2].h = __float22bfloat162_rn(make_float2(hi.x, hi.y));
                ua.p[3].h = __float22bfloat162_rn(make_float2(hi.z, hi.w));
#pragma unroll
                for (int ct = 0; ct < 2; ++ct)
                    acc[ra][ct] = __builtin_amdgcn_mfma_f32_16x16x32_bf16(
                        ua.v, breg[ks * 2 + ct], acc[ra][ct], 0, 0, 0);
            }
        }

        // ---- tanh-dot epilogue -> sred[colgroup][row] ----
#pragma unroll
        for (int ra = 0; ra < 2; ++ra) {
#pragma unroll
            for (int reg = 0; reg < 4; ++reg) {
                float s = fast_tanh(acc[ra][0][reg] + bc[0]) * wc[0]
                        + fast_tanh(acc[ra][1][reg] + bc[1]) * wc[1];
#pragma unroll
                for (int off = 1; off < 16; off <<= 1) s += __shfl_xor(s, off, 64);
                if (c16 == 0)
                    sred[wcg][arowb + ra * 16 + q * 4 + reg] = s;
            }
        }
        // sred visible to all waves; DMA keeps flying (no vmcnt drain here)
        asm volatile("s_waitcnt lgkmcnt(0)" ::: "memory");
        __builtin_amdgcn_s_barrier();

        // ---- online softmax: 1 row per lane, redundant in every wave ----
        float a = sred[0][lane] + sred[1][lane] + sred[2][lane] + sred[3][lane];
        a = mk ? a : NEGV;
        float mx = a;
#pragma unroll
        for (int off = 1; off < 64; off <<= 1) mx = fmaxf(mx, __shfl_xor(mx, off, 64));
        const float newm = fmaxf(m_run, mx);
        const float e = __expf(a - newm);
        float sm = e;
#pragma unroll
        for (int off = 1; off < 64; off <<= 1) sm += __shfl_xor(sm, off, 64);
        const float scale = __expf(m_run - newm);   // first tile: 0
        l_run = l_run * scale + sm;
        m_run = newm;
        Oac.x *= scale; Oac.y *= scale; Oac.z *= scale; Oac.w *= scale;

        // ---- weighted sum from LDS fp32: wave wv covers rows wv*8..+8 ----
#pragma unroll
        for (int r = 0; r < 8; ++r) {
            const int rw = wv * 8 + r;
            const float pl = __shfl(e, rw, 64);
            const float4 v = sA4[cur][rw * SR4 + lane];
            Oac.x += pl * v.x; Oac.y += pl * v.y; Oac.z += pl * v.z; Oac.w += pl * v.w;
        }
        cur ^= 1;
    }

    // ---- cross-wave reduce (reuse sA4), normalize, store ----
    __syncthreads();
    ((float4*)sA4)[t] = Oac;
    __syncthreads();
    if (t < 64) {
        float4 s = make_float4(0.f, 0.f, 0.f, 0.f);
#pragma unroll
        for (int j = 0; j < 8; ++j) {
            const float4 v = ((float4*)sA4)[j * 64 + t];
            s.x += v.x; s.y += v.y; s.z += v.z; s.w += v.w;
        }
        const float inv = 1.f / l_run;
        ((float4*)(outp + (size_t)pair * DIM))[t] =
            make_float4(s.x * inv, s.y * inv, s.z * inv, s.w * inv);
    }
}

// ---------------------------------------------------------------------------
extern "C" void kernel_launch(void* const* d_in, const int* in_sizes, int n_in,
                              void* d_out, int out_size, void* d_ws, size_t ws_size,
                              hipStream_t stream) {
    const float* claim    = (const float*)d_in[0];
    const int*   cmask    = (const int*)  d_in[1];
    const float* evidence = (const float*)d_in[2];
    const int*   emask    = (const int*)  d_in[3];
    const float* W1       = (const float*)d_in[4];
    const float* w2       = (const float*)d_in[5];
    const float* W2       = (const float*)d_in[6];
    const float* w1       = (const float*)d_in[7];
    float* out = (float*)d_out;

    float* ws = (float*)d_ws;
    float* bias_e = ws;                          // 256*128
    float* bias_c = bias_e + BE * OUTD;          // 256*128
    unsigned short* WT1 = (unsigned short*)(bias_c + BE * OUTD);
    unsigned short* WT2 = WT1 + OUTD * DIM;

    k_meanbias<<<BE + 2, 512, 0, stream>>>(claim, evidence, W1, W2,
                                           bias_e, bias_c, WT1, WT2);
    // output order: c_hat first (claim side), e_hat second (evidence side)
    k_fused<<<2 * BE, 512, 0, stream>>>(claim, evidence, WT1, WT2, w2, w1,
                                        bias_e, bias_c, emask, cmask, out);
}

// Round 7
// 330.770 us; speedup vs baseline: 1.2089x; 1.1194x over previous
//
#include <hip/hip_runtime.h>
#include <hip/hip_bf16.h>
#include <math.h>

#define BE   256
#define DIM  256
#define OUTD 128
#define LCL  256
#define LEV  512

#define NCH_EV 16              // 512/32 chunks per evidence pair
#define NCH_CL 8               // 256/32 chunks per claim pair
#define NCHP   (NCH_EV + NCH_CL)
#define NBLK   (BE * NCHP)     // 6144 partial blocks

typedef short  bf16x8  __attribute__((ext_vector_type(8)));
typedef float  floatx4 __attribute__((ext_vector_type(4)));

union BF1 { __hip_bfloat16 h; unsigned short u; };
union BF2 { __hip_bfloat162 h; unsigned int u; };

__device__ __forceinline__ float fast_tanh(float x) {
    float xc = fminf(fmaxf(x, -15.f), 15.f);
    float e = __expf(2.f * xc);                       // e^{2x}
    return (e - 1.f) * __builtin_amdgcn_rcpf(e + 1.f);
}

// Direct global->LDS DMA, 16B per lane. Dest is wave-uniform base
// (HW writes lane i at base + i*16); source is per-lane.
__device__ __forceinline__ void gl_lds16(const float4* g, float4* l) {
    __builtin_amdgcn_global_load_lds(
        (const __attribute__((address_space(1))) unsigned int*)(const void*)g,
        (__attribute__((address_space(3))) unsigned int*)(void*)l,
        16, 0, 0);
}

// ---------------------------------------------------------------------------
// K1: per-pair means (float4 streaming, unroll 8) + bias GEMVs + WT fold
// + per-side score bound M = sum_o |w[o]| (rigorous: |tanh|<1).
// blocks [0,256): pair b. blocks 256,257: W[:D] -> bf16 W^T and M.
// ---------------------------------------------------------------------------
__global__ __launch_bounds__(512) void k_meanbias(
    const float* __restrict__ claim, const float* __restrict__ evidence,
    const float* __restrict__ W1, const float* __restrict__ W2,
    const float* __restrict__ w2v, const float* __restrict__ w1v,
    float* __restrict__ bias_e, float* __restrict__ bias_c,
    unsigned short* __restrict__ WT1, unsigned short* __restrict__ WT2,
    float* __restrict__ Mval)
{
    const int bid = blockIdx.x;
    const int t = threadIdx.x;
    __shared__ float msum[8];
    if (bid >= BE) {
        const int side = bid - BE;
        const float* W = side ? W2 : W1;
        unsigned short* WT = side ? WT2 : WT1;
        for (int i = t; i < OUTD * DIM; i += 512) {
            const int d = i & (DIM - 1);
            const int n = i >> 8;
            BF1 c; c.h = __float2bfloat16(W[(size_t)d * OUTD + n]);
            WT[n * DIM + d] = c.u;
        }
        // M = sum |w| for this side's score vector (side0: w2, side1: w1)
        const float* wv_ = side ? w1v : w2v;
        float av = (t < OUTD) ? fabsf(wv_[t]) : 0.f;
#pragma unroll
        for (int off = 1; off < 64; off <<= 1) av += __shfl_xor(av, off, 64);
        if ((t & 63) == 0) msum[t >> 6] = av;
        __syncthreads();
        if (t == 0)
            Mval[side] = msum[0] + msum[1] + msum[2] + msum[3]
                       + msum[4] + msum[5] + msum[6] + msum[7];
        return;
    }
    const int pair = bid;
    const int d4 = t & 63, rg = t >> 6;      // 8 row groups
    __shared__ float4 smc[8][64];
    __shared__ float4 sme[8][64];
    __shared__ float mc[DIM], me[DIM];
    __shared__ float sb[2][2][OUTD];

    const float4* c4 = (const float4*)(claim + (size_t)pair * LCL * DIM);
    const float4* e4 = (const float4*)(evidence + (size_t)pair * LEV * DIM);
    float4 ac = make_float4(0.f, 0.f, 0.f, 0.f);
    float4 ae = make_float4(0.f, 0.f, 0.f, 0.f);
#pragma unroll 8
    for (int r = rg; r < LCL; r += 8) {
        const float4 v = c4[r * 64 + d4];
        ac.x += v.x; ac.y += v.y; ac.z += v.z; ac.w += v.w;
    }
#pragma unroll 8
    for (int r = rg; r < LEV; r += 8) {
        const float4 v = e4[r * 64 + d4];
        ae.x += v.x; ae.y += v.y; ae.z += v.z; ae.w += v.w;
    }
    smc[rg][d4] = ac; sme[rg][d4] = ae;
    __syncthreads();
    if (t < 64) {
        float4 s = make_float4(0.f, 0.f, 0.f, 0.f);
#pragma unroll
        for (int j = 0; j < 8; ++j) {
            const float4 v = smc[j][t];
            s.x += v.x; s.y += v.y; s.z += v.z; s.w += v.w;
        }
        ((float4*)mc)[t] = make_float4(s.x * (1.f / LCL), s.y * (1.f / LCL),
                                       s.z * (1.f / LCL), s.w * (1.f / LCL));
    } else if (t < 128) {
        const int u = t - 64;
        float4 s = make_float4(0.f, 0.f, 0.f, 0.f);
#pragma unroll
        for (int j = 0; j < 8; ++j) {
            const float4 v = sme[j][u];
            s.x += v.x; s.y += v.y; s.z += v.z; s.w += v.w;
        }
        ((float4*)me)[u] = make_float4(s.x * (1.f / LEV), s.y * (1.f / LEV),
                                       s.z * (1.f / LEV), s.w * (1.f / LEV));
    }
    __syncthreads();
    const int side = t >> 8, o = t & 127, dh = (t >> 7) & 1;
    const float* W = side ? W2 : W1;
    const float* m = side ? me : mc;
    float s = 0.f;
#pragma unroll 8
    for (int i = 0; i < 128; ++i) {
        const int d = dh * 128 + i;
        s += m[d] * W[(size_t)(DIM + d) * OUTD + o];
    }
    sb[side][dh][o] = s;
    __syncthreads();
    if (t < 256) {
        const int sd = t >> 7, oo = t & 127;
        const float bv = sb[sd][0][oo] + sb[sd][1][oo];
        (sd ? bias_c : bias_e)[pair * OUTD + oo] = bv;
    }
}

// ---------------------------------------------------------------------------
// K2: fully parallel partials. One block per 32-row CHUNK of one (pair,side):
// bid = pair*24 + c, c<16 -> evidence chunk c, else claim chunk c-16.
// 6144 blocks x 256 thr (4 waves), 33.8 KB LDS -> 4 blocks/CU, 16 waves/CU.
// Fixed-shift softmax e = exp(a - M) (M rigorous bound from k_meanbias) makes
// chunk partials (O_part, l_part) directly summable -> NO serial tile loop,
// NO online max/rescale, NO cross-tile barriers. Stage 32KB via DMA, one
// syncthreads, MFMA scores (verified fragment mapping), tanh-dot epilogue,
// e per lane, per-block l butterfly ONCE, fp32 wsum from LDS, write partial.
// ---------------------------------------------------------------------------
__global__ __launch_bounds__(256, 2) void k_main(
    const float* __restrict__ claim, const float* __restrict__ evidence,
    const unsigned short* __restrict__ WT1, const unsigned short* __restrict__ WT2,
    const float* __restrict__ w2v, const float* __restrict__ w1v,
    const float* __restrict__ bias_e, const float* __restrict__ bias_c,
    const int* __restrict__ emask, const int* __restrict__ cmask,
    const float* __restrict__ Mval,
    float* __restrict__ O_part, float* __restrict__ l_part)
{
    constexpr int TR  = 32;                 // chunk rows
    constexpr int SR4 = 65;                 // row stride in float4 (pad between rows)
    __shared__ float4 sA4[TR * SR4];        // 33280 B
    __shared__ float sred[4][TR];

    const int bid = blockIdx.x;
    const int pair = bid / NCHP;
    const int c = bid - pair * NCHP;
    const bool is_ev = c < NCH_EV;
    const int chunk = is_ev ? c : c - NCH_EV;
    const float* __restrict__ seq  = is_ev ? evidence : claim;
    const unsigned short* __restrict__ WT = is_ev ? WT1 : WT2;
    const float* __restrict__ wvec = is_ev ? w2v : w1v;
    const float* __restrict__ bias = is_ev ? bias_e : bias_c;
    const int*   __restrict__ mask = is_ev ? emask : cmask;
    const int L = is_ev ? LEV : LCL;
    const float M = Mval[is_ev ? 0 : 1];

    const int t = threadIdx.x;
    const int lane = t & 63;
    const int wv = t >> 6;                  // 0..3 = col group (32 cols each)
    const int q = lane >> 4, c16 = lane & 15;

    float bc[2], wc[2];
#pragma unroll
    for (int ct = 0; ct < 2; ++ct) {
        const int col = wv * 32 + ct * 16 + c16;
        bc[ct] = bias[pair * OUTD + col];
        wc[ct] = wvec[col];
    }
    // preload B fragments (WT is L1/L2-hot: 64 KB shared by all blocks)
    bf16x8 breg[16];
#pragma unroll
    for (int ks = 0; ks < 8; ++ks)
#pragma unroll
        for (int ct = 0; ct < 2; ++ct)
            breg[ks * 2 + ct] = *(const bf16x8*)(
                WT + (size_t)(wv * 32 + ct * 16 + c16) * DIM + ks * 32 + q * 8);

    // ---- stage this 32x256 fp32 chunk: wave wv DMAs rows wv*8..+8 ----
    const float4* base = (const float4*)(seq + ((size_t)pair * L + chunk * TR) * DIM);
#pragma unroll
    for (int j = 0; j < 8; ++j) {
        const int row = wv * 8 + j;
        gl_lds16(base + row * 64 + lane, &sA4[row * SR4]);
    }
    const int mk = mask[pair * L + chunk * TR + (lane & 31)];
    __syncthreads();                        // drains DMA (vmcnt0+lgkm0+barrier)

    // ---- MFMA scores: rows 0..32, cols wv*32..+32 (verified mapping) ----
    floatx4 acc[2][2];
    acc[0][0] = (floatx4){0.f, 0.f, 0.f, 0.f};
    acc[0][1] = (floatx4){0.f, 0.f, 0.f, 0.f};
    acc[1][0] = (floatx4){0.f, 0.f, 0.f, 0.f};
    acc[1][1] = (floatx4){0.f, 0.f, 0.f, 0.f};
#pragma unroll
    for (int ks = 0; ks < 8; ++ks) {
#pragma unroll
        for (int ra = 0; ra < 2; ++ra) {
            const float4 lo = sA4[(ra * 16 + c16) * SR4 + ks * 8 + q * 2];
            const float4 hi = sA4[(ra * 16 + c16) * SR4 + ks * 8 + q * 2 + 1];
            union { bf16x8 v; BF2 p[4]; } ua;
            ua.p[0].h = __float22bfloat162_rn(make_float2(lo.x, lo.y));
            ua.p[1].h = __float22bfloat162_rn(make_float2(lo.z, lo.w));
            ua.p[2].h = __float22bfloat162_rn(make_float2(hi.x, hi.y));
            ua.p[3].h = __float22bfloat162_rn(make_float2(hi.z, hi.w));
#pragma unroll
            for (int ct = 0; ct < 2; ++ct)
                acc[ra][ct] = __builtin_amdgcn_mfma_f32_16x16x32_bf16(
                    ua.v, breg[ks * 2 + ct], acc[ra][ct], 0, 0, 0);
        }
    }

    // ---- tanh-dot epilogue -> sred[colgroup][row] ----
#pragma unroll
    for (int ra = 0; ra < 2; ++ra) {
#pragma unroll
        for (int reg = 0; reg < 4; ++reg) {
            float s = fast_tanh(acc[ra][0][reg] + bc[0]) * wc[0]
                    + fast_tanh(acc[ra][1][reg] + bc[1]) * wc[1];
#pragma unroll
            for (int off = 1; off < 16; off <<= 1) s += __shfl_xor(s, off, 64);
            if (c16 == 0)
                sred[wv][ra * 16 + q * 4 + reg] = s;
        }
    }
    __syncthreads();

    // ---- fixed-shift softmax numerators: 1 row per lane (duplicated halves) ----
    const int r31 = lane & 31;
    const float a = sred[0][r31] + sred[1][r31] + sred[2][r31] + sred[3][r31];
    const float e = mk ? __expf(a - M) : 0.f;
    float sl = e;                           // chunk l: sum rows 0..31 (within halves)
#pragma unroll
    for (int off = 1; off < 32; off <<= 1) sl += __shfl_xor(sl, off, 64);

    // ---- weighted sum from LDS fp32: wave wv covers rows wv*8..+8 ----
    float4 Oac = make_float4(0.f, 0.f, 0.f, 0.f);
#pragma unroll
    for (int r = 0; r < 8; ++r) {
        const int rw = wv * 8 + r;
        const float pl = __shfl(e, rw, 64);
        const float4 v = sA4[rw * SR4 + lane];
        Oac.x += pl * v.x; Oac.y += pl * v.y; Oac.z += pl * v.z; Oac.w += pl * v.w;
    }

    // ---- cross-wave reduce (reuse sA4) and write partial ----
    __syncthreads();
    ((float4*)sA4)[t] = Oac;
    __syncthreads();
    if (t < 64) {
        float4 s = make_float4(0.f, 0.f, 0.f, 0.f);
#pragma unroll
        for (int j = 0; j < 4; ++j) {
            const float4 v = ((float4*)sA4)[j * 64 + t];
            s.x += v.x; s.y += v.y; s.z += v.z; s.w += v.w;
        }
        ((float4*)(O_part + (size_t)bid * DIM))[t] = s;
    }
    if (t == 0) l_part[bid] = sl;
}

// ---------------------------------------------------------------------------
// K3: combine chunk partials and normalize. One block per (pair,side).
// even bid = evidence -> e_hat (out + BE*DIM); odd = claim -> c_hat (out).
// ---------------------------------------------------------------------------
__global__ __launch_bounds__(64) void k_combine(
    const float* __restrict__ O_part, const float* __restrict__ l_part,
    float* __restrict__ out)
{
    const int bid = blockIdx.x;
    const int t = threadIdx.x;
    const bool is_ev = (bid & 1) == 0;
    const int pair = bid >> 1;
    const int base = pair * NCHP + (is_ev ? 0 : NCH_EV);
    const int NC = is_ev ? NCH_EV : NCH_CL;
    float* __restrict__ outp = is_ev ? out + (size_t)BE * DIM : out;

    float4 s = make_float4(0.f, 0.f, 0.f, 0.f);
    float l = 0.f;
    for (int i = 0; i < NC; ++i) {
        const float4 v = ((const float4*)(O_part + (size_t)(base + i) * DIM))[t];
        s.x += v.x; s.y += v.y; s.z += v.z; s.w += v.w;
        l += l_part[base + i];
    }
    const float inv = 1.f / l;
    ((float4*)(outp + (size_t)pair * DIM))[t] =
        make_float4(s.x * inv, s.y * inv, s.z * inv, s.w * inv);
}

// ---------------------------------------------------------------------------
extern "C" void kernel_launch(void* const* d_in, const int* in_sizes, int n_in,
                              void* d_out, int out_size, void* d_ws, size_t ws_size,
                              hipStream_t stream) {
    const float* claim    = (const float*)d_in[0];
    const int*   cmask    = (const int*)  d_in[1];
    const float* evidence = (const float*)d_in[2];
    const int*   emask    = (const int*)  d_in[3];
    const float* W1       = (const float*)d_in[4];
    const float* w2       = (const float*)d_in[5];
    const float* W2       = (const float*)d_in[6];
    const float* w1       = (const float*)d_in[7];
    float* out = (float*)d_out;

    float* ws = (float*)d_ws;
    float* bias_e = ws;                          // 256*128
    float* bias_c = bias_e + BE * OUTD;          // 256*128
    float* O_part = bias_c + BE * OUTD;          // 6144*256
    float* l_part = O_part + (size_t)NBLK * DIM; // 6144
    float* Mval   = l_part + NBLK;               // 2
    unsigned short* WT1 = (unsigned short*)(Mval + 2);
    unsigned short* WT2 = WT1 + OUTD * DIM;

    k_meanbias<<<BE + 2, 512, 0, stream>>>(claim, evidence, W1, W2, w2, w1,
                                           bias_e, bias_c, WT1, WT2, Mval);
    k_main<<<NBLK, 256, 0, stream>>>(claim, evidence, WT1, WT2, w2, w1,
                                     bias_e, bias_c, emask, cmask, Mval,
                                     O_part, l_part);
    // output order: c_hat first (claim side), e_hat second (evidence side)
    k_combine<<<2 * BE, 64, 0, stream>>>(O_part, l_part, out);
}